// Round 10
// baseline (80.970 us; speedup 1.0000x reference)
//
#include <hip/hip_runtime.h>
#include <hip/hip_bf16.h>
#include <math.h>

#define BB 16
#define TT 2048
#define DD 1024
#define HH 64
#define QK_SCALE 0.18033688011112042f  // 0.125 * log2(e)  (exp2-domain softmax)

typedef short bf16x8 __attribute__((ext_vector_type(8)));
typedef short bf16x4 __attribute__((ext_vector_type(4)));
typedef float f32x4 __attribute__((ext_vector_type(4)));

__device__ __forceinline__ short f2bf(float f) {  // RNE (cold paths only)
  union { float f; unsigned u; } c; c.f = f;
  unsigned u = c.u + 0x7FFFu + ((c.u >> 16) & 1u);
  return (short)(u >> 16);
}

// packed pair f32x2 -> bf16x2 (v_cvt_pk_bf16_f32 via standard cast API, m240)
__device__ __forceinline__ unsigned pk2(float lo, float hi) {
  float2 t; t.x = lo; t.y = hi;
  __hip_bfloat162 h = __float22bfloat162_rn(t);
  union { __hip_bfloat162 h; unsigned u; } c; c.h = h;
  return c.u;
}

// 64-col bf16 tile (128B row stride): XOR-swizzle 16B units by row&7.
__device__ __forceinline__ void* lds_swz(void* base, int row, int col) {
  int byte = (row << 7) + (col << 1);
  byte ^= (row & 7) << 4;
  return (void*)((char*)base + byte);
}

__device__ __forceinline__ void pack16(const float4& a0, const float4& a1,
                                       const float4& a2, const float4& a3,
                                       bf16x8& s0, bf16x8& s1) {
  unsigned* u0 = (unsigned*)&s0;
  unsigned* u1 = (unsigned*)&s1;
  u0[0] = pk2(a0.x, a0.y); u0[1] = pk2(a0.z, a0.w);
  u0[2] = pk2(a1.x, a1.y); u0[3] = pk2(a1.z, a1.w);
  u1[0] = pk2(a2.x, a2.y); u1[1] = pk2(a2.z, a2.w);
  u1[2] = pk2(a3.x, a3.y); u1[3] = pk2(a3.z, a3.w);
}

// ---------------------------------------------------------------------------
// Pack Wq|Wk|Wv (fp32 [D][H]) -> Wt bf16 [192][1024]  (n-major, k contiguous)
// ---------------------------------------------------------------------------
__global__ __launch_bounds__(256) void pack_wt(
    const float* __restrict__ Wq, const float* __restrict__ Wk,
    const float* __restrict__ Wv, short* __restrict__ wt) {
  const int idx = blockIdx.x * 256 + threadIdx.x;
  const int n = idx >> 7;
  const int k0 = (idx & 127) << 3;
  const float* W = (n < 64) ? Wq : (n < 128) ? Wk : Wv;
  const int h = n & 63;
  bf16x8 o;
#pragma unroll
  for (int j = 0; j < 8; ++j) o[j] = f2bf(W[(k0 + j) * HH + h]);
  *(bf16x8*)&wt[n * DD + k0] = o;
}

// ---------------------------------------------------------------------------
// QKV GEMM, bf16 MFMA, depth-2 x prefetch, cvt_pk packing. Q pre-scaled by
// QK_SCALE; V written transposed to vt [b][h][t].
// ---------------------------------------------------------------------------
__global__ __launch_bounds__(256) void qkv_mfma(
    const float* __restrict__ x, const short* __restrict__ wt,
    short* __restrict__ qo, short* __restrict__ ko, short* __restrict__ vt) {
  __shared__ short xs[2][64 * 64];
  const int tid = threadIdx.x;
  const int lane = tid & 63;
  const int w = tid >> 6;
  const int q16 = lane & 15;
  const int g = lane >> 4;
  const size_t r0 = (size_t)blockIdx.x * 64;

  const int srow = tid >> 2;
  const int sc = (tid & 3) << 4;
  const float* xrow = x + (r0 + srow) * DD + sc;

  f32x4 acc[4][3];
#pragma unroll
  for (int mf = 0; mf < 4; ++mf)
#pragma unroll
    for (int nf = 0; nf < 3; ++nf) acc[mf][nf] = (f32x4){0.f, 0.f, 0.f, 0.f};

  const short* wp[3];
#pragma unroll
  for (int nf = 0; nf < 3; ++nf)
    wp[nf] = wt + (size_t)(w * 48 + nf * 16 + q16) * DD + g * 8;

  float4 xa[2][4];  // two in-flight x reg-sets (unroll-2 keeps idx static)
  {
    const float4* xp = (const float4*)xrow;
#pragma unroll
    for (int j = 0; j < 4; ++j) xa[0][j] = xp[j];
    bf16x8 s0, s1;
    pack16(xa[0][0], xa[0][1], xa[0][2], xa[0][3], s0, s1);
    *(bf16x8*)lds_swz(xs[0], srow, sc) = s0;
    *(bf16x8*)lds_swz(xs[0], srow, sc + 8) = s1;
    const float4* xp1 = (const float4*)(xrow + 64);
#pragma unroll
    for (int j = 0; j < 4; ++j) xa[1][j] = xp1[j];
  }
  bf16x8 bcur[3][2];
#pragma unroll
  for (int nf = 0; nf < 3; ++nf)
#pragma unroll
    for (int kf = 0; kf < 2; ++kf)
      bcur[nf][kf] = *(const bf16x8*)(wp[nf] + kf * 32);
  __syncthreads();

  int cur = 0;
#pragma unroll 2
  for (int ks = 0; ks < 16; ++ks) {
    const int pnext = (ks + 1) & 1;  // set holding x(ks+1)
    const int pfree = ks & 1;        // set to refill with x(ks+2)
    if (ks < 14) {
      const float4* xp = (const float4*)(xrow + (ks + 2) * 64);
#pragma unroll
      for (int j = 0; j < 4; ++j) xa[pfree][j] = xp[j];
    }
    bf16x8 bnxt[3][2];
    if (ks < 15) {
      const int k1 = (ks + 1) << 6;
#pragma unroll
      for (int nf = 0; nf < 3; ++nf)
#pragma unroll
        for (int kf = 0; kf < 2; ++kf)
          bnxt[nf][kf] = *(const bf16x8*)(wp[nf] + k1 + kf * 32);
    }

    bf16x8 afr[4][2];
#pragma unroll
    for (int mf = 0; mf < 4; ++mf)
#pragma unroll
      for (int kf = 0; kf < 2; ++kf)
        afr[mf][kf] = *(bf16x8*)lds_swz(xs[cur], mf * 16 + q16, kf * 32 + g * 8);

#pragma unroll
    for (int mf = 0; mf < 4; ++mf)
#pragma unroll
      for (int nf = 0; nf < 3; ++nf)
#pragma unroll
        for (int kf = 0; kf < 2; ++kf)
          acc[mf][nf] = __builtin_amdgcn_mfma_f32_16x16x32_bf16(
              afr[mf][kf], bcur[nf][kf], acc[mf][nf], 0, 0, 0);

    if (ks < 15) {
      bf16x8 s0, s1;
      pack16(xa[pnext][0], xa[pnext][1], xa[pnext][2], xa[pnext][3], s0, s1);
      *(bf16x8*)lds_swz(xs[cur ^ 1], srow, sc) = s0;
      *(bf16x8*)lds_swz(xs[cur ^ 1], srow, sc + 8) = s1;
      __syncthreads();
      cur ^= 1;
#pragma unroll
      for (int nf = 0; nf < 3; ++nf)
#pragma unroll
        for (int kf = 0; kf < 2; ++kf) bcur[nf][kf] = bnxt[nf][kf];
    }
  }

#pragma unroll
  for (int nf = 0; nf < 3; ++nf) {
    const int n = w * 48 + nf * 16 + q16;
    const int mat = n >> 6;  // frag-uniform
    const int h = n & 63;
    if (mat < 2) {
      short* outp = mat ? ko : qo;
      const float fac = mat ? 1.0f : QK_SCALE;
#pragma unroll
      for (int mf = 0; mf < 4; ++mf)
#pragma unroll
        for (int r = 0; r < 4; ++r)
          outp[(r0 + mf * 16 + g * 4 + r) * HH + h] = f2bf(acc[mf][nf][r] * fac);
    } else {
      const int bb = (int)(r0 >> 11);
      const int tloc = (int)(r0 & 2047);
#pragma unroll
      for (int mf = 0; mf < 4; ++mf) {
        uint2 pkv;
        pkv.x = pk2(acc[mf][nf][0], acc[mf][nf][1]);
        pkv.y = pk2(acc[mf][nf][2], acc[mf][nf][3]);
        *(uint2*)&vt[((size_t)bb * HH + h) * TT + tloc + mf * 16 + g * 4] = pkv;
      }
    }
  }
}

// ---------------------------------------------------------------------------
// Flash attention, bf16 MFMA, swapped-QK + in-register P (cvt_pk P-pack).
// 1D grid (512) with XCD swizzle; V^T staged with key->slot permutation so
// each PV B-frag is ONE ds_read_b128. Identical structure to round 9.
// ---------------------------------------------------------------------------
__global__ __launch_bounds__(256, 4) void attn_mfma(
    const short* __restrict__ q, const short* __restrict__ k,
    const short* __restrict__ vt, float* __restrict__ out) {
  __shared__ short klds[2][64 * 64];  // 16 KB, K [key][d] (buf0 also Q stage)
  __shared__ short vlds[2][64 * 64];  // 16 KB, V^T [h][slot] permuted

  const int id = blockIdx.x;  // 0..511
  const int b = (id & 7) | (((id >> 3) & 1) << 3);
  const int kk = id >> 4;     // 0..31
  const int qt = (kk < 16) ? (31 - kk) : (kk - 16);
  const int t0 = qt << 6;
  const int tid = threadIdx.x;
  const int lane = tid & 63;
  const int w = tid >> 6;  // 0..3, wave owns q rows t0+w*16..+15
  const int q16 = lane & 15;
  const int g = lane >> 4;
  const int NC = qt + 1;  // 64-key chunks

  const size_t brow = (size_t)b * TT;
  const short* kg = k + brow * HH;
  const short* vtg = vt + (size_t)b * HH * TT;

  const int srow = tid >> 2;        // 0..63
  const int scol = (tid & 3) << 4;  // 0,16,32,48 (elements / slots)

  // V permuted staging constants: groups A (slots scol..+7), B (scol+8..+15)
  const int vgA = (scol >> 3) & 3;   // g-bits of group A
  const int vgB = ((scol + 8) >> 3) & 3;
  const int vm2 = scol >> 5;         // m2 bit
  const short* vrow_p = vtg + srow * TT + vm2 * 32;

  // issue chunk-0 K/V loads first (hide under Q staging)
  bf16x8 kr0 = *(const bf16x8*)&kg[srow * HH + scol];
  bf16x8 kr1 = *(const bf16x8*)&kg[srow * HH + scol + 8];
  bf16x4 va0 = *(const bf16x4*)(vrow_p + 4 * vgA);
  bf16x4 va1 = *(const bf16x4*)(vrow_p + 16 + 4 * vgA);
  bf16x4 vb0 = *(const bf16x4*)(vrow_p + 4 * vgB);
  bf16x4 vb1 = *(const bf16x4*)(vrow_p + 16 + 4 * vgB);

  // stage Q tile into klds[0], pull per-wave Q frags (B-operand layout)
  {
    const short* qsrc = q + (brow + t0 + srow) * HH;
    *(bf16x8*)lds_swz(klds[0], srow, scol) = *(const bf16x8*)&qsrc[scol];
    *(bf16x8*)lds_swz(klds[0], srow, scol + 8) = *(const bf16x8*)&qsrc[scol + 8];
  }
  __syncthreads();
  bf16x8 qa[2];
#pragma unroll
  for (int kf = 0; kf < 2; ++kf)
    qa[kf] = *(bf16x8*)lds_swz(klds[0], w * 16 + q16, kf * 32 + g * 8);
  __syncthreads();

  // write chunk 0
  *(bf16x8*)lds_swz(klds[0], srow, scol) = kr0;
  *(bf16x8*)lds_swz(klds[0], srow, scol + 8) = kr1;
  *(bf16x8*)lds_swz(vlds[0], srow, scol) =
      __builtin_shufflevector(va0, va1, 0, 1, 2, 3, 4, 5, 6, 7);
  *(bf16x8*)lds_swz(vlds[0], srow, scol + 8) =
      __builtin_shufflevector(vb0, vb1, 0, 1, 2, 3, 4, 5, 6, 7);
  __syncthreads();

  f32x4 po[4];  // O[q=4g+r][h=nf*16+q16]
  f32x4 lacc = (f32x4){0.f, 0.f, 0.f, 0.f};
  float m = -INFINITY;  // per-lane frame: q = q16 (S^T column), g-uniform
#pragma unroll
  for (int nf = 0; nf < 4; ++nf) po[nf] = (f32x4){0.f, 0.f, 0.f, 0.f};

  const bf16x8 ones = {0x3F80, 0x3F80, 0x3F80, 0x3F80,
                       0x3F80, 0x3F80, 0x3F80, 0x3F80};
  int cur = 0;

  for (int c = 0; c < NC; ++c) {
    const bool notlast = (c + 1 < NC);
    if (notlast) {  // T14: issue next chunk's globals before compute
      const int s1 = (c + 1) << 6;
      kr0 = *(const bf16x8*)&kg[(s1 + srow) * HH + scol];
      kr1 = *(const bf16x8*)&kg[(s1 + srow) * HH + scol + 8];
      va0 = *(const bf16x4*)(vrow_p + s1 + 4 * vgA);
      va1 = *(const bf16x4*)(vrow_p + s1 + 16 + 4 * vgA);
      vb0 = *(const bf16x4*)(vrow_p + s1 + 4 * vgB);
      vb1 = *(const bf16x4*)(vrow_p + s1 + 16 + 4 * vgB);
    }

    // ---- S^T = K . Q^T (swapped operands; Q pre-scaled for exp2) ----
    f32x4 sfr[4];
#pragma unroll
    for (int nf = 0; nf < 4; ++nf) sfr[nf] = (f32x4){0.f, 0.f, 0.f, 0.f};
    __builtin_amdgcn_s_setprio(1);
#pragma unroll
    for (int nf = 0; nf < 4; ++nf)
#pragma unroll
      for (int kf = 0; kf < 2; ++kf) {
        bf16x8 kb = *(bf16x8*)lds_swz(klds[cur], nf * 16 + q16, kf * 32 + g * 8);
        sfr[nf] = __builtin_amdgcn_mfma_f32_16x16x32_bf16(kb, qa[kf], sfr[nf], 0, 0, 0);
      }
    __builtin_amdgcn_s_setprio(0);

    // ---- causal mask (diagonal chunk only): key 16nf+4g+r > w*16+q16 ----
    if (c == NC - 1) {
      const int qloc = w * 16 + q16;
#pragma unroll
      for (int nf = 0; nf < 4; ++nf)
#pragma unroll
        for (int r = 0; r < 4; ++r)
          if (16 * nf + 4 * g + r > qloc) sfr[nf][r] = -INFINITY;
    }

    // ---- row max: per-lane over its 16 keys, then across g-groups ----
    float pm;
    {
      f32x4 t01 = (f32x4){fmaxf(sfr[0][0], sfr[1][0]), fmaxf(sfr[0][1], sfr[1][1]),
                          fmaxf(sfr[0][2], sfr[1][2]), fmaxf(sfr[0][3], sfr[1][3])};
      f32x4 t23 = (f32x4){fmaxf(sfr[2][0], sfr[3][0]), fmaxf(sfr[2][1], sfr[3][1]),
                          fmaxf(sfr[2][2], sfr[3][2]), fmaxf(sfr[2][3], sfr[3][3])};
      pm = fmaxf(fmaxf(fmaxf(t01[0], t23[0]), fmaxf(t01[1], t23[1])),
                 fmaxf(fmaxf(t01[2], t23[2]), fmaxf(t01[3], t23[3])));
      pm = fmaxf(pm, __shfl_xor(pm, 16));
      pm = fmaxf(pm, __shfl_xor(pm, 32));
    }

    // ---- defer-max (T13, THR=8 in log2 units) ----
    if (__any(pm - m > 8.f)) {
      const float mn = fmaxf(m, pm);
      const float corr = exp2f(m - mn);  // 0 on first chunk
      m = mn;
      const int sbase = (lane & 48) + ((lane >> 4) << 2);
#pragma unroll
      for (int r = 0; r < 4; ++r) {
        const float cr = __shfl(corr, sbase + r);
        lacc[r] *= cr;
#pragma unroll
        for (int nf = 0; nf < 4; ++nf) po[nf][r] *= cr;
      }
    }

    // ---- P = exp2(S - m) -> bf16 A-frags via cvt_pk (no LDS) ----
    bf16x8 pa[2];
#pragma unroll
    for (int m2 = 0; m2 < 2; ++m2) {
      float e0 = exp2f(sfr[2 * m2][0] - m), e1 = exp2f(sfr[2 * m2][1] - m);
      float e2 = exp2f(sfr[2 * m2][2] - m), e3 = exp2f(sfr[2 * m2][3] - m);
      float e4 = exp2f(sfr[2 * m2 + 1][0] - m), e5 = exp2f(sfr[2 * m2 + 1][1] - m);
      float e6 = exp2f(sfr[2 * m2 + 1][2] - m), e7 = exp2f(sfr[2 * m2 + 1][3] - m);
      unsigned* up = (unsigned*)&pa[m2];
      up[0] = pk2(e0, e1); up[1] = pk2(e2, e3);
      up[2] = pk2(e4, e5); up[3] = pk2(e6, e7);
    }

    // ---- O += P.V ; l += P.1  (permuted V: one b128 per B-frag) ----
    __builtin_amdgcn_s_setprio(1);
#pragma unroll
    for (int m2 = 0; m2 < 2; ++m2) {
#pragma unroll
      for (int nf = 0; nf < 4; ++nf) {
        bf16x8 vb = *(bf16x8*)lds_swz(vlds[cur], nf * 16 + q16, m2 * 32 + g * 8);
        po[nf] = __builtin_amdgcn_mfma_f32_16x16x32_bf16(pa[m2], vb, po[nf], 0, 0, 0);
      }
      lacc = __builtin_amdgcn_mfma_f32_16x16x32_bf16(pa[m2], ones, lacc, 0, 0, 0);
    }
    __builtin_amdgcn_s_setprio(0);

    if (notlast) {
      *(bf16x8*)lds_swz(klds[cur ^ 1], srow, scol) = kr0;
      *(bf16x8*)lds_swz(klds[cur ^ 1], srow, scol + 8) = kr1;
      *(bf16x8*)lds_swz(vlds[cur ^ 1], srow, scol) =
          __builtin_shufflevector(va0, va1, 0, 1, 2, 3, 4, 5, 6, 7);
      *(bf16x8*)lds_swz(vlds[cur ^ 1], srow, scol + 8) =
          __builtin_shufflevector(vb0, vb1, 0, 1, 2, 3, 4, 5, 6, 7);
      __syncthreads();
      cur ^= 1;
    }
  }

  const int qrow = t0 + w * 16 + g * 4;
#pragma unroll
  for (int nf = 0; nf < 4; ++nf) {
    const int h = nf * 16 + q16;
#pragma unroll
    for (int r = 0; r < 4; ++r)
      out[(brow + qrow + r) * HH + h] = po[nf][r] / lacc[r];
  }
}

extern "C" void kernel_launch(void* const* d_in, const int* in_sizes, int n_in,
                              void* d_out, int out_size, void* d_ws, size_t ws_size,
                              hipStream_t stream) {
  const float* x  = (const float*)d_in[0];
  const float* Wq = (const float*)d_in[1];
  const float* Wk = (const float*)d_in[2];
  const float* Wv = (const float*)d_in[3];
  float* out = (float*)d_out;

  const size_t bth = (size_t)BB * TT * HH;  // 2,097,152
  short* qb  = (short*)d_ws;
  short* kb  = qb + bth;
  short* vtb = kb + bth;
  short* wtb = vtb + bth;  // 192*1024 bf16

  pack_wt<<<96, 256, 0, stream>>>(Wq, Wk, Wv, wtb);
  qkv_mfma<<<(BB * TT) / 64, 256, 0, stream>>>(x, wtb, qb, kb, vtb);
  attn_mfma<<<512, 256, 0, stream>>>(qb, kb, vtb, out);
}